// Round 10
// baseline (152.851 us; speedup 1.0000x reference)
//
#include <hip/hip_runtime.h>
#include <hip/hip_bf16.h>

#define NH 32
#define DH 128
#define DIMM 4096
#define TCTX 16384
#define BSZ 8
#define NBLK_TOT (TCTX / BSZ)   // 2048
#define MB_SEL 145
#define SINK_TOK 60
#define WIN_TOK 60
#define BLK_CAP 192             // >= 161, padded
#define NSPLIT 27               // 6 blocks per split
#define CHUNK 6
#define PSTRIDE (DH + 2)        // per-(head,split) partial: o[128], m, l
#define KV_WGS 1024             // 8192 kv rows / 8
#define SC_WG_PER_H 128         // 2048 blocks / 16 per WG
#define SC_WGS (NH * SC_WG_PER_H)

typedef __attribute__((ext_vector_type(4))) float f4v;

__device__ __forceinline__ float4 ntload4(const float* p) {
    f4v v = __builtin_nontemporal_load((const f4v*)p);
    return make_float4(v.x, v.y, v.z, v.w);
}

// dot of TWO weight rows against x (x read via cache, no LDS, no barrier)
__device__ __forceinline__ void gemv_row2(const float* __restrict__ wr0,
                                          const float* __restrict__ wr1,
                                          const float* __restrict__ x, int lane,
                                          float& o0, float& o1) {
    float a0 = 0.f, a1 = 0.f;
    #pragma unroll
    for (int it = 0; it < 16; ++it) {
        int j = lane * 4 + it * 256;
        float4 xv = *(const float4*)(x + j);
        float4 w0 = ntload4(wr0 + j);
        float4 w1 = ntload4(wr1 + j);
        a0 += w0.x * xv.x + w0.y * xv.y + w0.z * xv.z + w0.w * xv.w;
        a1 += w1.x * xv.x + w1.y * xv.y + w1.z * xv.z + w1.w * xv.w;
    }
    #pragma unroll
    for (int m = 1; m < 64; m <<= 1) {
        a0 += __shfl_xor(a0, m, 64);
        a1 += __shfl_xor(a1, m, 64);
    }
    o0 = a0; o1 = a1;
}

// ---------------- kernel 1: q-rows GEMV + RoPE; zeroes tail counters -------------
__global__ __launch_bounds__(256) void k_q(const float* __restrict__ x,
                                           const float* __restrict__ w,
                                           const float* __restrict__ freqs,
                                           float* __restrict__ q1,
                                           unsigned int* __restrict__ cnts) {
    int t = threadIdx.x;
    if (blockIdx.x == 0 && t < NH) cnts[t * 16] = 0u;   // 64B-padded counters
    int wave = t >> 6, lane = t & 63;
    int r0 = blockIdx.x * 8 + wave * 2;          // even
    float a0, a1;
    gemv_row2(w + (size_t)r0 * DIMM, w + (size_t)(r0 + 1) * DIMM, x, lane, a0, a1);
    if (lane == 0) {
        int m = (r0 >> 1) & 63;
        float fr = freqs[2 * m], fi = freqs[2 * m + 1];
        float2 o; o.x = a0 * fr - a1 * fi; o.y = a1 * fr + a0 * fi;
        *(float2*)(q1 + r0) = o;
    }
}

// ---------------- kernel 2: fused kv-GEMV (+RoPE) || block-mean scores ----------
__global__ __launch_bounds__(256) void k_mid(const float* __restrict__ x,
                                             const float* __restrict__ w,
                                             const float* __restrict__ freqs,
                                             const float* __restrict__ q1,
                                             const float* __restrict__ kc,
                                             const int* __restrict__ ip_p,
                                             float* __restrict__ kn,
                                             float* __restrict__ vn,
                                             float* __restrict__ scores) {
    int t = threadIdx.x, wave = t >> 6, lane = t & 63;

    if (blockIdx.x < KV_WGS) {
        // ---- k/v rows GEMV; rows [4096, 12288), 8 per WG, 2 per wave ----
        int r0 = DIMM + blockIdx.x * 8 + wave * 2;   // even
        float a0, a1;
        gemv_row2(w + (size_t)r0 * DIMM, w + (size_t)(r0 + 1) * DIMM, x, lane, a0, a1);
        if (lane == 0) {
            if (r0 < 2 * DIMM) {           // k rows: RoPE
                int m = (r0 >> 1) & 63;
                float fr = freqs[2 * m], fi = freqs[2 * m + 1];
                float2 o; o.x = a0 * fr - a1 * fi; o.y = a1 * fr + a0 * fi;
                *(float2*)(kn + (r0 - DIMM)) = o;
            } else {                        // v rows: copy
                float2 o; o.x = a0; o.y = a1;
                *(float2*)(vn + (r0 - 2 * DIMM)) = o;
            }
        }
        return;
    }

    // ---- block-mean scores: 4 blocks per wave (16 KB contiguous) ----
    int ip = *ip_p;
    int T = ip + 1;
    int Tb = T / BSZ;
    int sidx = blockIdx.x - KV_WGS;
    int h = sidx >> 7;                  // 128 WGs per head
    int wg = sidx & 127;
    int b0 = wg * 16 + wave * 4;        // first of 4 blocks
    int d0 = (lane * 4) & 127;
    float4 q4 = *(const float4*)(q1 + h * DH + d0);
    const float* kb = kc + ((size_t)h * TCTX + (size_t)b0 * BSZ) * DH;
    float acc[4] = {0.f, 0.f, 0.f, 0.f};
    #pragma unroll
    for (int i = 0; i < 16; ++i) {
        float4 k4 = *(const float4*)(kb + lane * 4 + i * 256);
        acc[i >> 2] += q4.x * k4.x + q4.y * k4.y + q4.z * k4.z + q4.w * k4.w;
    }
    #pragma unroll
    for (int m = 1; m < 64; m <<= 1) {
        acc[0] += __shfl_xor(acc[0], m, 64);
        acc[1] += __shfl_xor(acc[1], m, 64);
        acc[2] += __shfl_xor(acc[2], m, 64);
        acc[3] += __shfl_xor(acc[3], m, 64);
    }
    if (lane == 0) {
        float4 out;
        out.x = (b0 + 0 < Tb) ? acc[0] * 0.011048543456039805f : -1e30f;
        out.y = (b0 + 1 < Tb) ? acc[1] * 0.011048543456039805f : -1e30f;
        out.z = (b0 + 2 < Tb) ? acc[2] * 0.011048543456039805f : -1e30f;
        out.w = (b0 + 3 < Tb) ? acc[3] * 0.011048543456039805f : -1e30f;
        *(float4*)(scores + h * NBLK_TOT + b0) = out;
    }
}

// ------- kernel 3: gathered attention + fused top-k (recompute) + tail reduce -----
__global__ __launch_bounds__(256) void k_attn(const float* __restrict__ q1,
                                              const float* __restrict__ kc,
                                              const float* __restrict__ vc,
                                              const float* __restrict__ kn,
                                              const float* __restrict__ vn,
                                              const float* __restrict__ scores,
                                              const int* __restrict__ ip_p,
                                              float* __restrict__ part,
                                              float* __restrict__ o,
                                              unsigned int* __restrict__ cnts) {
    __shared__ int bl_s[BLK_CAP];
    __shared__ float oacc[4][DH];
    __shared__ float2 ml_s[4];
    __shared__ int tailflag;
    int h = blockIdx.x / NSPLIT;
    int sp = blockIdx.x % NSPLIT;
    int t = threadIdx.x, wave = t >> 6, lane = t & 63;
    int g = lane >> 4, sub = lane & 15;
    int ip = *ip_p;
    int T = ip + 1;
    int Tb = T / BSZ;
    int sink_b = min((min(SINK_TOK, T) + BSZ - 1) / BSZ, Tb);
    int window_b = min((min(WIN_TOK, T) + BSZ - 1) / BSZ, Tb);
    int cur = (T - 1) / BSZ;
    int win_start = max(0, cur - window_b + 1);
    int win_end = cur + 1;
    int nwin = win_end - win_start;
    int nblk = sink_b + nwin + MB_SEL;            // 161
    int b0 = sp * CHUNK;
    int nb = min(nblk - b0, CHUNK);
    float* pp = part + ((size_t)h * NSPLIT + sp) * PSTRIDE;

    // ---- wave 0: recompute this head's top-k block list into LDS ----
    if (wave == 0) {
        unsigned int u[32];
        const float* sh = scores + h * NBLK_TOT;
        #pragma unroll
        for (int i = 0; i < 32; i += 4) {
            float4 sv = *(const float4*)(sh + lane * 32 + i);
            float fv[4] = {sv.x, sv.y, sv.z, sv.w};
            #pragma unroll
            for (int q = 0; q < 4; ++q) {
                int j = lane * 32 + i + q;
                unsigned int b = __float_as_uint(fv[q]);
                unsigned int m = (b & 0x80000000u) ? ~b : (b | 0x80000000u);
                bool ok = (j < Tb) && (j >= sink_b) && !(j >= win_start && j < win_end);
                u[i + q] = ok ? m : 0u;
            }
        }
        unsigned int lo = 0u, hi = 0xFFFFFFFFu;
        while (lo < hi) {
            unsigned int mid =
                (unsigned int)(((unsigned long long)lo + (unsigned long long)hi + 1ull) >> 1);
            int c = 0;
            #pragma unroll
            for (int i = 0; i < 32; ++i) c += (u[i] >= mid);
            #pragma unroll
            for (int m = 1; m < 64; m <<= 1) c += __shfl_xor(c, m, 64);
            if (c >= MB_SEL) lo = mid; else hi = mid - 1;
        }
        int gt = 0, eq = 0;
        #pragma unroll
        for (int i = 0; i < 32; ++i) { gt += (u[i] > lo); eq += (u[i] == lo); }
        unsigned int packed = ((unsigned int)gt << 16) | (unsigned int)eq;
        unsigned int sc = packed;
        #pragma unroll
        for (int off = 1; off < 64; off <<= 1) {
            unsigned int v = __shfl_up(sc, off, 64);
            if (lane >= off) sc += v;
        }
        unsigned int tot = __shfl(sc, 63, 64);
        unsigned int totg = tot >> 16;
        unsigned int excl = sc - packed;
        int gi = (int)(excl >> 16);
        int ei = (int)(excl & 0xFFFFu);
        int need_eq = MB_SEL - (int)totg;
        int base = sink_b + nwin;
        for (int i = lane; i < base; i += 64)
            bl_s[i] = (i < sink_b) ? i : (win_start + (i - sink_b));
        #pragma unroll
        for (int i = 0; i < 32; ++i) {
            int j = lane * 32 + i;
            if (u[i] > lo) {
                bl_s[base + gi] = j; ++gi;
            } else if (u[i] == lo) {
                if (ei < need_eq) bl_s[base + (int)totg + ei] = j;
                ++ei;
            }
        }
    }
    __syncthreads();

    // ---- single-pass online-softmax gather over this split's blocks ----
    float4 qa = *(const float4*)(q1 + h * DH + sub * 8);
    float4 qb = *(const float4*)(q1 + h * DH + sub * 8 + 4);
    const float* kh = kc + (size_t)h * TCTX * DH;
    const float* vh = vc + (size_t)h * TCTX * DH;

    float m = -1e30f, l = 0.f;
    float4 aa = make_float4(0, 0, 0, 0), ab = make_float4(0, 0, 0, 0);

    for (int c = wave; c < nb * 2; c += 4) {
        int blk = bl_s[b0 + (c >> 1)];
        int tok = blk * BSZ + (c & 1) * 4 + g;
        const float* kr = (tok == ip) ? (kn + h * DH) : (kh + (size_t)tok * DH);
        const float* vr = (tok == ip) ? (vn + h * DH) : (vh + (size_t)tok * DH);
        float4 ka  = *(const float4*)(kr + sub * 8);
        float4 kb2 = *(const float4*)(kr + sub * 8 + 4);
        float4 va  = *(const float4*)(vr + sub * 8);
        float4 vb  = *(const float4*)(vr + sub * 8 + 4);
        float s = qa.x * ka.x + qa.y * ka.y + qa.z * ka.z + qa.w * ka.w +
                  qb.x * kb2.x + qb.y * kb2.y + qb.z * kb2.z + qb.w * kb2.w;
        s += __shfl_xor(s, 1, 64);
        s += __shfl_xor(s, 2, 64);
        s += __shfl_xor(s, 4, 64);
        s += __shfl_xor(s, 8, 64);
        s *= 0.08838834764831845f;
        float mn = fmaxf(m, s);
        float cf = __expf(m - mn);
        float w  = __expf(s - mn);
        l = l * cf + w;
        aa.x = aa.x * cf + w * va.x; aa.y = aa.y * cf + w * va.y;
        aa.z = aa.z * cf + w * va.z; aa.w = aa.w * cf + w * va.w;
        ab.x = ab.x * cf + w * vb.x; ab.y = ab.y * cf + w * vb.y;
        ab.z = ab.z * cf + w * vb.z; ab.w = ab.w * cf + w * vb.w;
        m = mn;
    }

    #pragma unroll
    for (int off = 16; off < 64; off <<= 1) {
        float mo = __shfl_xor(m, off, 64);
        float lo_ = __shfl_xor(l, off, 64);
        float4 oa, ob;
        oa.x = __shfl_xor(aa.x, off, 64); oa.y = __shfl_xor(aa.y, off, 64);
        oa.z = __shfl_xor(aa.z, off, 64); oa.w = __shfl_xor(aa.w, off, 64);
        ob.x = __shfl_xor(ab.x, off, 64); ob.y = __shfl_xor(ab.y, off, 64);
        ob.z = __shfl_xor(ab.z, off, 64); ob.w = __shfl_xor(ab.w, off, 64);
        float mn = fmaxf(m, mo);
        float c1 = __expf(m - mn), c2 = __expf(mo - mn);
        l = l * c1 + lo_ * c2;
        aa.x = aa.x * c1 + oa.x * c2; aa.y = aa.y * c1 + oa.y * c2;
        aa.z = aa.z * c1 + oa.z * c2; aa.w = aa.w * c1 + oa.w * c2;
        ab.x = ab.x * c1 + ob.x * c2; ab.y = ab.y * c1 + ob.y * c2;
        ab.z = ab.z * c1 + ob.z * c2; ab.w = ab.w * c1 + ob.w * c2;
        m = mn;
    }

    if (g == 0) {
        oacc[wave][sub * 8 + 0] = aa.x; oacc[wave][sub * 8 + 1] = aa.y;
        oacc[wave][sub * 8 + 2] = aa.z; oacc[wave][sub * 8 + 3] = aa.w;
        oacc[wave][sub * 8 + 4] = ab.x; oacc[wave][sub * 8 + 5] = ab.y;
        oacc[wave][sub * 8 + 6] = ab.z; oacc[wave][sub * 8 + 7] = ab.w;
    }
    if (lane == 0) ml_s[wave] = make_float2(m, l);
    __syncthreads();

    if (t < DH + 2) {
        float M = fmaxf(fmaxf(ml_s[0].x, ml_s[1].x), fmaxf(ml_s[2].x, ml_s[3].x));
        float L = 0.f, acc = 0.f;
        #pragma unroll
        for (int wv = 0; wv < 4; ++wv) {
            float cw = __expf(ml_s[wv].x - M);
            L += ml_s[wv].y * cw;
            if (t < DH) acc += oacc[wv][t] * cw;
        }
        if (t < DH) pp[t] = acc;
        else if (t == DH) pp[DH] = M;
        else pp[DH + 1] = L;
    }

    // ---- tail: last split of this head combines the 27 partials ----
    __syncthreads();
    if (t == 0) {
        __threadfence();                              // release pp writes
        unsigned int old = atomicAdd(&cnts[h * 16], 1u);
        tailflag = (old == NSPLIT - 1) ? 1 : 0;
    }
    __syncthreads();
    if (tailflag && t < DH) {
        __threadfence();                              // acquire sibling partials
        const float* ph = part + (size_t)h * NSPLIT * PSTRIDE;
        float M = -1e30f;
        for (int s = 0; s < NSPLIT; ++s) M = fmaxf(M, ph[s * PSTRIDE + DH]);
        float L = 0.f, acc = 0.f;
        for (int s = 0; s < NSPLIT; ++s) {
            float w = __expf(ph[s * PSTRIDE + DH] - M);
            L += ph[s * PSTRIDE + DH + 1] * w;
            acc += ph[s * PSTRIDE + t] * w;
        }
        o[h * DH + t] = acc / L;
    }
}

// ---------------- kernel 4: output projection (8 rows/WG, 2/wave) ----------------
__global__ __launch_bounds__(256) void k_gemv_o(const float* __restrict__ x,
                                                const float* __restrict__ w,
                                                float* __restrict__ out) {
    int t = threadIdx.x;
    int wave = t >> 6, lane = t & 63;
    int r0 = blockIdx.x * 8 + wave * 2;
    float a0, a1;
    gemv_row2(w + (size_t)r0 * DIMM, w + (size_t)(r0 + 1) * DIMM, x, lane, a0, a1);
    if (lane == 0) {
        float2 o; o.x = a0; o.y = a1;
        *(float2*)(out + r0) = o;
    }
}

extern "C" void kernel_launch(void* const* d_in, const int* in_sizes, int n_in,
                              void* d_out, int out_size, void* d_ws, size_t ws_size,
                              hipStream_t stream) {
    const float* x     = (const float*)d_in[0];
    const float* freqs = (const float*)d_in[1];
    const float* wqkv  = (const float*)d_in[2];
    const float* wo    = (const float*)d_in[3];
    const float* kc    = (const float*)d_in[4];
    const float* vc    = (const float*)d_in[5];
    const int*   ip    = (const int*)d_in[6];
    float* y = (float*)d_out;

    float* ws     = (float*)d_ws;
    float* q1     = ws;                    // 4096
    float* kn     = ws + 4096;             // 4096
    float* vn     = ws + 8192;             // 4096
    float* scores = ws + 12288;            // 65536
    float* part   = ws + 77824;            // 32*27*130 = 112320
    float* o      = ws + 190144;           // 4096
    unsigned int* cnts = (unsigned int*)(ws + 194240);  // 32 * 16 (64B-padded)

    // 1) q rows GEMV + RoPE (also zeroes tail counters)
    k_q<<<DIMM / 8, 256, 0, stream>>>(x, wqkv, freqs, q1, cnts);
    // 2) fused: kv rows GEMV (+RoPE) || block-mean score scan
    k_mid<<<KV_WGS + SC_WGS, 256, 0, stream>>>(x, wqkv, freqs, q1, kc, ip,
                                               kn, vn, scores);
    // 3) gathered attention with fused per-WG top-k recompute + tail reduce
    k_attn<<<NH * NSPLIT, 256, 0, stream>>>(q1, kc, vc, kn, vn, scores, ip,
                                            part, o, cnts);
    // 4) y = o @ wo.T
    k_gemv_o<<<DIMM / 8, 256, 0, stream>>>(o, wo, y);
}

// Round 11
// 123.192 us; speedup vs baseline: 1.2408x; 1.2408x over previous
//
#include <hip/hip_runtime.h>
#include <hip/hip_bf16.h>

#define NH 32
#define DH 128
#define DIMM 4096
#define TCTX 16384
#define BSZ 8
#define NBLK_TOT (TCTX / BSZ)   // 2048
#define MB_SEL 145
#define SINK_TOK 60
#define WIN_TOK 60
#define BLK_CAP 192             // >= 161, padded
#define NSPLIT 27               // 6 blocks per split
#define CHUNK 6
#define PSTRIDE (DH + 2)        // per-(head,split) partial: o[128], m, l
#define SC_WG_PER_H 128         // 2048 blocks / 16 per WG
#define SC_WGS (NH * SC_WG_PER_H)

typedef __attribute__((ext_vector_type(4))) float f4v;

__device__ __forceinline__ float4 ntload4(const float* p) {
    f4v v = __builtin_nontemporal_load((const f4v*)p);
    return make_float4(v.x, v.y, v.z, v.w);
}

// dot of TWO weight rows against x (x read via cache, no LDS, no barrier)
__device__ __forceinline__ void gemv_row2(const float* __restrict__ wr0,
                                          const float* __restrict__ wr1,
                                          const float* __restrict__ x, int lane,
                                          float& o0, float& o1) {
    float a0 = 0.f, a1 = 0.f;
    #pragma unroll
    for (int it = 0; it < 16; ++it) {
        int j = lane * 4 + it * 256;
        float4 xv = *(const float4*)(x + j);
        float4 w0 = ntload4(wr0 + j);
        float4 w1 = ntload4(wr1 + j);
        a0 += w0.x * xv.x + w0.y * xv.y + w0.z * xv.z + w0.w * xv.w;
        a1 += w1.x * xv.x + w1.y * xv.y + w1.z * xv.z + w1.w * xv.w;
    }
    #pragma unroll
    for (int m = 1; m < 64; m <<= 1) {
        a0 += __shfl_xor(a0, m, 64);
        a1 += __shfl_xor(a1, m, 64);
    }
    o0 = a0; o1 = a1;
}

// ------- kernel 1: FULL qkv GEMV + RoPE (12288 rows, 8/WG, 2/wave, 1536 WGs) -------
__global__ __launch_bounds__(256) void k_qkv(const float* __restrict__ x,
                                             const float* __restrict__ w,
                                             const float* __restrict__ freqs,
                                             float* __restrict__ q1,
                                             float* __restrict__ kn,
                                             float* __restrict__ vn) {
    int t = threadIdx.x;
    int wave = t >> 6, lane = t & 63;
    int r0 = blockIdx.x * 8 + wave * 2;          // even
    float a0, a1;
    gemv_row2(w + (size_t)r0 * DIMM, w + (size_t)(r0 + 1) * DIMM, x, lane, a0, a1);
    if (lane == 0) {
        if (r0 < 2 * DIMM) {                     // q or k rows: RoPE
            int m = (r0 >> 1) & 63;
            float fr = freqs[2 * m], fi = freqs[2 * m + 1];
            float2 o; o.x = a0 * fr - a1 * fi; o.y = a1 * fr + a0 * fi;
            if (r0 < DIMM) *(float2*)(q1 + r0) = o;
            else           *(float2*)(kn + (r0 - DIMM)) = o;
        } else {                                 // v rows: copy
            float2 o; o.x = a0; o.y = a1;
            *(float2*)(vn + (r0 - 2 * DIMM)) = o;
        }
    }
}

// ---------------- kernel 2: block-mean scores (4 blocks/wave, 4096 WGs) ----------
__global__ __launch_bounds__(256) void k_scores(const float* __restrict__ q1,
                                                const float* __restrict__ kc,
                                                const int* __restrict__ ip_p,
                                                float* __restrict__ scores) {
    int t = threadIdx.x, wave = t >> 6, lane = t & 63;
    int ip = *ip_p;
    int T = ip + 1;
    int Tb = T / BSZ;
    int h = blockIdx.x >> 7;            // 128 WGs per head
    int wg = blockIdx.x & 127;
    int b0 = wg * 16 + wave * 4;        // first of 4 blocks
    int d0 = (lane * 4) & 127;
    float4 q4 = *(const float4*)(q1 + h * DH + d0);
    const float* kb = kc + ((size_t)h * TCTX + (size_t)b0 * BSZ) * DH;
    float acc[4] = {0.f, 0.f, 0.f, 0.f};
    #pragma unroll
    for (int i = 0; i < 16; ++i) {
        float4 k4 = *(const float4*)(kb + lane * 4 + i * 256);
        acc[i >> 2] += q4.x * k4.x + q4.y * k4.y + q4.z * k4.z + q4.w * k4.w;
    }
    #pragma unroll
    for (int m = 1; m < 64; m <<= 1) {
        acc[0] += __shfl_xor(acc[0], m, 64);
        acc[1] += __shfl_xor(acc[1], m, 64);
        acc[2] += __shfl_xor(acc[2], m, 64);
        acc[3] += __shfl_xor(acc[3], m, 64);
    }
    if (lane == 0) {
        float4 out;
        out.x = (b0 + 0 < Tb) ? acc[0] * 0.011048543456039805f : -1e30f;
        out.y = (b0 + 1 < Tb) ? acc[1] * 0.011048543456039805f : -1e30f;
        out.z = (b0 + 2 < Tb) ? acc[2] * 0.011048543456039805f : -1e30f;
        out.w = (b0 + 3 < Tb) ? acc[3] * 0.011048543456039805f : -1e30f;
        *(float4*)(scores + h * NBLK_TOT + b0) = out;
    }
}

// ---------------- top-k selection: ONE WAVE per head, all in registers ----
__global__ __launch_bounds__(64) void k_topk(const float* __restrict__ scores,
                                             const int* __restrict__ ip_p,
                                             int* __restrict__ blklist) {
    int h = blockIdx.x;
    int lane = threadIdx.x & 63;
    int ip = *ip_p;
    int T = ip + 1;
    int Tb = T / BSZ;
    int sink_b = min((min(SINK_TOK, T) + BSZ - 1) / BSZ, Tb);
    int window_b = min((min(WIN_TOK, T) + BSZ - 1) / BSZ, Tb);
    int cur = (T - 1) / BSZ;
    int win_start = max(0, cur - window_b + 1);
    int win_end = cur + 1;

    unsigned int u[32];
    const float* sh = scores + h * NBLK_TOT;
    #pragma unroll
    for (int i = 0; i < 32; i += 4) {
        float4 sv = *(const float4*)(sh + lane * 32 + i);
        float fv[4] = {sv.x, sv.y, sv.z, sv.w};
        #pragma unroll
        for (int q = 0; q < 4; ++q) {
            int j = lane * 32 + i + q;
            unsigned int b = __float_as_uint(fv[q]);
            unsigned int m = (b & 0x80000000u) ? ~b : (b | 0x80000000u);
            bool ok = (j < Tb) && (j >= sink_b) && !(j >= win_start && j < win_end);
            u[i + q] = ok ? m : 0u;
        }
    }

    unsigned int lo = 0u, hi = 0xFFFFFFFFu;
    while (lo < hi) {
        unsigned int mid =
            (unsigned int)(((unsigned long long)lo + (unsigned long long)hi + 1ull) >> 1);
        int c = 0;
        #pragma unroll
        for (int i = 0; i < 32; ++i) c += (u[i] >= mid);
        #pragma unroll
        for (int m = 1; m < 64; m <<= 1) c += __shfl_xor(c, m, 64);
        if (c >= MB_SEL) lo = mid; else hi = mid - 1;
    }

    int gt = 0, eq = 0;
    #pragma unroll
    for (int i = 0; i < 32; ++i) { gt += (u[i] > lo); eq += (u[i] == lo); }
    unsigned int packed = ((unsigned int)gt << 16) | (unsigned int)eq;
    unsigned int sc = packed;
    #pragma unroll
    for (int off = 1; off < 64; off <<= 1) {
        unsigned int v = __shfl_up(sc, off, 64);
        if (lane >= off) sc += v;
    }
    unsigned int tot = __shfl(sc, 63, 64);
    unsigned int totg = tot >> 16;
    unsigned int excl = sc - packed;
    int gi = (int)(excl >> 16);
    int ei = (int)(excl & 0xFFFFu);
    int need_eq = MB_SEL - (int)totg;

    int base = sink_b + (win_end - win_start);
    int* bl = blklist + h * BLK_CAP;
    for (int i = lane; i < base; i += 64)
        bl[i] = (i < sink_b) ? i : (win_start + (i - sink_b));

    #pragma unroll
    for (int i = 0; i < 32; ++i) {
        int j = lane * 32 + i;
        if (u[i] > lo) {
            bl[base + gi] = j; ++gi;
        } else if (u[i] == lo) {
            if (ei < need_eq) bl[base + (int)totg + ei] = j;
            ++ei;
        }
    }
}

// ------- gathered attention: single-pass online softmax, 1 barrier per WG -------
__global__ __launch_bounds__(256) void k_attn_part(const float* __restrict__ q1,
                                                   const float* __restrict__ kc,
                                                   const float* __restrict__ vc,
                                                   const float* __restrict__ kn,
                                                   const float* __restrict__ vn,
                                                   const int* __restrict__ blklist,
                                                   const int* __restrict__ ip_p,
                                                   float* __restrict__ part) {
    __shared__ float oacc[4][DH];
    __shared__ float2 ml_s[4];
    int h = blockIdx.x / NSPLIT;
    int sp = blockIdx.x % NSPLIT;
    int t = threadIdx.x, wave = t >> 6, lane = t & 63;
    int g = lane >> 4, sub = lane & 15;
    int ip = *ip_p;
    int T = ip + 1;
    int Tb = T / BSZ;
    int sink_b = min((min(SINK_TOK, T) + BSZ - 1) / BSZ, Tb);
    int window_b = min((min(WIN_TOK, T) + BSZ - 1) / BSZ, Tb);
    int cur = (T - 1) / BSZ;
    int win_start = max(0, cur - window_b + 1);
    int nwin = cur + 1 - win_start;
    int nblk = sink_b + nwin + MB_SEL;            // 161
    int b0 = sp * CHUNK;
    int nb = min(nblk - b0, CHUNK);
    float* pp = part + ((size_t)h * NSPLIT + sp) * PSTRIDE;
    if (nb <= 0) {
        if (t < DH) pp[t] = 0.f;
        if (t == DH) pp[DH] = -1e30f;
        if (t == DH + 1) pp[DH + 1] = 0.f;
        return;
    }

    float4 qa = *(const float4*)(q1 + h * DH + sub * 8);
    float4 qb = *(const float4*)(q1 + h * DH + sub * 8 + 4);
    const float* kh = kc + (size_t)h * TCTX * DH;
    const float* vh = vc + (size_t)h * TCTX * DH;
    const int* bl = blklist + h * BLK_CAP + b0;

    float m = -1e30f, l = 0.f;
    float4 aa = make_float4(0, 0, 0, 0), ab = make_float4(0, 0, 0, 0);

    for (int c = wave; c < nb * 2; c += 4) {
        int blk = bl[c >> 1];
        int tok = blk * BSZ + (c & 1) * 4 + g;
        const float* kr = (tok == ip) ? (kn + h * DH) : (kh + (size_t)tok * DH);
        const float* vr = (tok == ip) ? (vn + h * DH) : (vh + (size_t)tok * DH);
        float4 ka  = *(const float4*)(kr + sub * 8);
        float4 kb2 = *(const float4*)(kr + sub * 8 + 4);
        float4 va  = *(const float4*)(vr + sub * 8);
        float4 vb  = *(const float4*)(vr + sub * 8 + 4);
        float s = qa.x * ka.x + qa.y * ka.y + qa.z * ka.z + qa.w * ka.w +
                  qb.x * kb2.x + qb.y * kb2.y + qb.z * kb2.z + qb.w * kb2.w;
        s += __shfl_xor(s, 1, 64);
        s += __shfl_xor(s, 2, 64);
        s += __shfl_xor(s, 4, 64);
        s += __shfl_xor(s, 8, 64);
        s *= 0.08838834764831845f;
        float mn = fmaxf(m, s);
        float cf = __expf(m - mn);
        float w  = __expf(s - mn);
        l = l * cf + w;
        aa.x = aa.x * cf + w * va.x; aa.y = aa.y * cf + w * va.y;
        aa.z = aa.z * cf + w * va.z; aa.w = aa.w * cf + w * va.w;
        ab.x = ab.x * cf + w * vb.x; ab.y = ab.y * cf + w * vb.y;
        ab.z = ab.z * cf + w * vb.z; ab.w = ab.w * cf + w * vb.w;
        m = mn;
    }

    #pragma unroll
    for (int off = 16; off < 64; off <<= 1) {
        float mo = __shfl_xor(m, off, 64);
        float lo_ = __shfl_xor(l, off, 64);
        float4 oa, ob;
        oa.x = __shfl_xor(aa.x, off, 64); oa.y = __shfl_xor(aa.y, off, 64);
        oa.z = __shfl_xor(aa.z, off, 64); oa.w = __shfl_xor(aa.w, off, 64);
        ob.x = __shfl_xor(ab.x, off, 64); ob.y = __shfl_xor(ab.y, off, 64);
        ob.z = __shfl_xor(ab.z, off, 64); ob.w = __shfl_xor(ab.w, off, 64);
        float mn = fmaxf(m, mo);
        float c1 = __expf(m - mn), c2 = __expf(mo - mn);
        l = l * c1 + lo_ * c2;
        aa.x = aa.x * c1 + oa.x * c2; aa.y = aa.y * c1 + oa.y * c2;
        aa.z = aa.z * c1 + oa.z * c2; aa.w = aa.w * c1 + oa.w * c2;
        ab.x = ab.x * c1 + ob.x * c2; ab.y = ab.y * c1 + ob.y * c2;
        ab.z = ab.z * c1 + ob.z * c2; ab.w = ab.w * c1 + ob.w * c2;
        m = mn;
    }

    if (g == 0) {
        oacc[wave][sub * 8 + 0] = aa.x; oacc[wave][sub * 8 + 1] = aa.y;
        oacc[wave][sub * 8 + 2] = aa.z; oacc[wave][sub * 8 + 3] = aa.w;
        oacc[wave][sub * 8 + 4] = ab.x; oacc[wave][sub * 8 + 5] = ab.y;
        oacc[wave][sub * 8 + 6] = ab.z; oacc[wave][sub * 8 + 7] = ab.w;
    }
    if (lane == 0) ml_s[wave] = make_float2(m, l);
    __syncthreads();

    if (t < DH + 2) {
        float M = fmaxf(fmaxf(ml_s[0].x, ml_s[1].x), fmaxf(ml_s[2].x, ml_s[3].x));
        float L = 0.f, acc = 0.f;
        #pragma unroll
        for (int wv = 0; wv < 4; ++wv) {
            float cw = __expf(ml_s[wv].x - M);
            L += ml_s[wv].y * cw;
            if (t < DH) acc += oacc[wv][t] * cw;
        }
        if (t < DH) pp[t] = acc;
        else if (t == DH) pp[DH] = M;
        else pp[DH + 1] = L;
    }
}

// ---------------- combine partials ----------------
__global__ __launch_bounds__(128) void k_attn_reduce(const float* __restrict__ part,
                                                     float* __restrict__ o) {
    int h = blockIdx.x, t = threadIdx.x;
    const float* ph = part + (size_t)h * NSPLIT * PSTRIDE;
    float M = -1e30f;
    #pragma unroll 9
    for (int s = 0; s < NSPLIT; ++s) M = fmaxf(M, ph[s * PSTRIDE + DH]);
    float L = 0.f, acc = 0.f;
    #pragma unroll 9
    for (int s = 0; s < NSPLIT; ++s) {
        float w = __expf(ph[s * PSTRIDE + DH] - M);
        L += ph[s * PSTRIDE + DH + 1] * w;
        acc += ph[s * PSTRIDE + t] * w;
    }
    o[h * DH + t] = acc / L;
}

// ---------------- output projection (8 rows/WG, 2/wave) ----------------
__global__ __launch_bounds__(256) void k_gemv_o(const float* __restrict__ x,
                                                const float* __restrict__ w,
                                                float* __restrict__ out) {
    int t = threadIdx.x;
    int wave = t >> 6, lane = t & 63;
    int r0 = blockIdx.x * 8 + wave * 2;
    float a0, a1;
    gemv_row2(w + (size_t)r0 * DIMM, w + (size_t)(r0 + 1) * DIMM, x, lane, a0, a1);
    if (lane == 0) {
        float2 o; o.x = a0; o.y = a1;
        *(float2*)(out + r0) = o;
    }
}

extern "C" void kernel_launch(void* const* d_in, const int* in_sizes, int n_in,
                              void* d_out, int out_size, void* d_ws, size_t ws_size,
                              hipStream_t stream) {
    const float* x     = (const float*)d_in[0];
    const float* freqs = (const float*)d_in[1];
    const float* wqkv  = (const float*)d_in[2];
    const float* wo    = (const float*)d_in[3];
    const float* kc    = (const float*)d_in[4];
    const float* vc    = (const float*)d_in[5];
    const int*   ip    = (const int*)d_in[6];
    float* y = (float*)d_out;

    float* ws     = (float*)d_ws;
    float* q1     = ws;                    // 4096
    float* kn     = ws + 4096;             // 4096
    float* vn     = ws + 8192;             // 4096
    float* scores = ws + 12288;            // 65536
    float* part   = ws + 77824;            // 32*27*130 = 112320
    float* o      = ws + 190144;           // 4096
    int*   blkl   = (int*)(ws + 194240);   // 32*192 ints

    // 1) full qkv GEMV + RoPE (1536 WGs = 24 waves/CU on the 201 MB stream)
    k_qkv<<<3 * DIMM / 8, 256, 0, stream>>>(x, wqkv, freqs, q1, kn, vn);
    // 2) block-mean score scan (4096 WGs = 32 waves/CU on the 256 MB stream)
    k_scores<<<SC_WGS, 256, 0, stream>>>(q1, kc, ip, scores);
    // 3) per-head top-k block selection (one wave per head)
    k_topk<<<NH, 64, 0, stream>>>(scores, ip, blkl);
    // 4) gathered attention: online-softmax single pass, 27 splits/head
    k_attn_part<<<NH * NSPLIT, 256, 0, stream>>>(q1, kc, vc, kn, vn, blkl, ip, part);
    // 5) combine partials
    k_attn_reduce<<<NH, 128, 0, stream>>>(part, o);
    // 6) y = o @ wo.T (2 rows/wave)
    k_gemv_o<<<DIMM / 8, 256, 0, stream>>>(o, wo, y);
}